// Round 7
// baseline (596.391 us; speedup 1.0000x reference)
//
#include <hip/hip_runtime.h>

#define T_STEPS 512

typedef __attribute__((ext_vector_type(8))) short s16x8;  // 8 bf16 (4 VGPRs)
typedef __attribute__((ext_vector_type(4))) float f32x4;  // MFMA C/D

__device__ __forceinline__ short f2bf(float v) {          // fp32 -> bf16 RNE
    unsigned u = __float_as_uint(v);
    return (short)((u + 0x7FFFu + ((u >> 16) & 1u)) >> 16);
}
__device__ __forceinline__ float bf2f(short b) {
    return __uint_as_float(((unsigned)(unsigned short)b) << 16);
}
__device__ __forceinline__ float sigf(float x)  { return 1.f / (1.f + __expf(-x)); }
__device__ __forceinline__ float tanhf_(float x){ float e = __expf(2.f * x); return 1.f - 2.f / (e + 1.f); }

// Block: 4 batches, 512 threads = 8 waves; grid = 256 -> 1 block/CU.
// r6 post-mortem: both phases were single-pipe (MFMA-only, then trans-only)
// -> ~80% dependency stall. This version INTERLEAVES THE LAYERS so every
// phase has an MFMA stream and an independent VALU/trans stream (MFMA+VALU
// pipes co-issue, m114):
//   Phase A(i): MFMA0 gates0(i)=f(x(i),h0(i-1))  ||  CELL1 h1(i-2)  || x-stage
//   Phase B(i): CELL0 h0(i)                      ||  MFMA1 gates1(i-1)
// L1 lags L0 by 2 steps (loop runs to i=513). h0 B-frags (t1,t2) are read
// once in PA and reused by MFMA1 in PB (values, not re-reads). gbuf0/gbuf1
// single-buffered (write->barrier->read->barrier->write). Barriers: 2/iter.
// B-col clamp: cols 0-3 real; lanes n16>=4 broadcast col 3 (garbage only in
// D-cols 4-15, never read). bB stride 176 -> B-read bases 2 req/bank (free).
__global__ __launch_bounds__(512, 2)
void lstm2_mfma(const float* __restrict__ x,
                const float* __restrict__ Wih0, const float* __restrict__ Whh0,
                const float* __restrict__ bih0, const float* __restrict__ bhh0,
                const float* __restrict__ Wih1, const float* __restrict__ Whh1,
                const float* __restrict__ bih1, const float* __restrict__ bhh1,
                const float* __restrict__ Wfc,  const float* __restrict__ bfc,
                float* __restrict__ out)
{
    // merged B buffer, bf16, [parity][n(4)][k]: x 0..31 | h0 32..95 | h1 96..159
    // parity p=i&1: bB[p].x=x(i), bB[p].h0=h0(i-1), bB[p].h1=h1(i-2) (written
    // by CELL1 in PA(i), read by MFMA1 in PB(i) across the phase barrier).
    __shared__ __align__(16) short bB[2][4][176];
    // gate buffers: [state*4 + batch] -> f32x4 (i,f,g,o), bias in C-seed
    __shared__ __align__(16) float gbuf0[256 * 4];   // L0: PA-write, PB-read
    __shared__ __align__(16) float gbuf1[256 * 4];   // L1: PB-write, PA-read

    const int tid  = threadIdx.x;
    const int w    = tid >> 6;       // wave 0..7
    const int lane = tid & 63;
    const int n16  = lane & 15;      // MFMA col (batch for n<4) / A-row m
    const int q4   = lane >> 4;      // quad: D-state-slot; A k-run
    const int b0   = blockIdx.x * 4;

    // ---- A fragments: two 16-row tiles per layer. Tile t row m -> gate m&3,
    //      state 8w + 4t + (m>>2). ----
    s16x8 a0[2], a1[2], a2[2];       // L0: K=96  {x, h0_lo, h0_hi}
    s16x8 e0[2], e1[2], e2[2], e3[2];// L1: K=128 {h0_lo, h0_hi, h1_lo, h1_hi}
    f32x4 bias0[2], bias1[2];
#pragma unroll
    for (int t = 0; t < 2; ++t) {
        const int rowW = (n16 & 3) * 64 + 8 * w + 4 * t + (n16 >> 2);
#pragma unroll
        for (int j = 0; j < 8; ++j) {
            a0[t][j] = f2bf(Wih0[rowW * 32 + q4 * 8 + j]);
            a1[t][j] = f2bf(Whh0[rowW * 64 + q4 * 8 + j]);
            a2[t][j] = f2bf(Whh0[rowW * 64 + 32 + q4 * 8 + j]);
            e0[t][j] = f2bf(Wih1[rowW * 64 + q4 * 8 + j]);
            e1[t][j] = f2bf(Wih1[rowW * 64 + 32 + q4 * 8 + j]);
            e2[t][j] = f2bf(Whh1[rowW * 64 + q4 * 8 + j]);
            e3[t][j] = f2bf(Whh1[rowW * 64 + 32 + q4 * 8 + j]);
        }
        const int jl = 8 * w + 4 * t + q4;   // state whose gates tile t's D holds
#pragma unroll
        for (int p_ = 0; p_ < 4; ++p_) {
            bias0[t][p_] = bih0[p_ * 64 + jl] + bhh0[p_ * 64 + jl];
            bias1[t][p_] = bih1[p_ * 64 + jl] + bhh1[p_ * 64 + jl];
        }
    }

    // ---- gate-buffer indices (writes: lanes n16<4) ----
    const int gw0 = ((8 * w + q4) * 4 + n16) * 4;        // tile0
    const int gw1 = ((8 * w + 4 + q4) * 4 + n16) * 4;    // tile1
    const int cw  = w & 3;                   // cell sub-wave id within group
    const int cs  = 16 * cw + (lane >> 2);   // cell state 0..63
    const int cb  = lane & 3;                // cell batch 0..3
    const int gri = 64 * cw + lane;          // == cs*4 + cb (consecutive b128)

    // ---- B-read column clamp ----
    const int nB  = (n16 < 4) ? n16 : 3;

    // ---- x stagers: waves 0-1 (MFMA-only in PA otherwise). Wave w stages
    //      batches 2w,2w+1; full-lane: 2 batches x 32 k. Register pipeline:
    //      load x(i+2) at PA(i) top, commit x(i+1) at PA(i) end. ----
    const bool isx = (w < 2);
    const int  xb  = w * 2 + (lane >> 5);    // 0..3
    const int  xk  = lane & 31;
    const float* xp = x + ((size_t)(b0 + xb) * T_STEPS) * 32 + xk;

    // ---- init: zero B buffer; stage x(0); preload x(1) ----
    for (int i = tid; i < 2 * 4 * 176 / 2; i += 512) ((int*)bB)[i] = 0;
    __syncthreads();
    float xreg = 0.f;
    if (isx) {
        bB[0][xb][xk] = f2bf(xp[0]);
        xreg = xp[32];               // x(1)
    }
    __syncthreads();

    float cst0 = 0.f, cst1 = 0.f;    // fp32 cell states (waves 0-3 / 4-7)

    for (int it = 0; it <= T_STEPS + 1; ++it) {
        const int p = it & 1;

        float xnew = 0.f;
        if (isx && it + 2 < T_STEPS) xnew = xp[(size_t)(it + 2) * 32];

        // ======== Phase A: MFMA0 (all waves) || CELL1 (waves 4-7) ========
        const short* bp = &bB[p][nB][q4 * 8];
        s16x8 t0 = *(const s16x8*)(bp);          // x(it)
        s16x8 t1 = *(const s16x8*)(bp + 32);     // h0(it-1) lo  (reused in PB)
        s16x8 t2 = *(const s16x8*)(bp + 64);     // h0(it-1) hi  (reused in PB)

        if (it < T_STEPS) {          // gates0(it)
            f32x4 d0a = __builtin_amdgcn_mfma_f32_16x16x32_bf16(a0[0], t0, bias0[0], 0, 0, 0);
            f32x4 d0b = __builtin_amdgcn_mfma_f32_16x16x32_bf16(a0[1], t0, bias0[1], 0, 0, 0);
            d0a = __builtin_amdgcn_mfma_f32_16x16x32_bf16(a1[0], t1, d0a, 0, 0, 0);
            d0b = __builtin_amdgcn_mfma_f32_16x16x32_bf16(a1[1], t1, d0b, 0, 0, 0);
            d0a = __builtin_amdgcn_mfma_f32_16x16x32_bf16(a2[0], t2, d0a, 0, 0, 0);
            d0b = __builtin_amdgcn_mfma_f32_16x16x32_bf16(a2[1], t2, d0b, 0, 0, 0);
            if (n16 < 4) {
                *(f32x4*)&gbuf0[gw0] = d0a;
                *(f32x4*)&gbuf0[gw1] = d0b;
            }
        }
        if (w >= 4 && it >= 2) {     // CELL1: h1(it-2), 256 cells full-lane
            f32x4 g = *(const f32x4*)&gbuf1[gri * 4];
            float cc = sigf(g[1]) * cst1 + sigf(g[0]) * tanhf_(g[2]);
            cst1 = cc;
            bB[p][cb][96 + cs] = f2bf(sigf(g[3]) * tanhf_(cc));  // read by PB(it)
        }
        if (isx && it + 1 < T_STEPS) bB[p ^ 1][xb][xk] = f2bf(xreg);  // x(it+1)
        __syncthreads();             // gates0 + h1 + x visible

        // ======== Phase B: CELL0 (waves 0-3) || MFMA1 (all waves) ========
        s16x8 t3 = *(const s16x8*)(bp + 96);     // h1(it-2) lo (written in PA)
        s16x8 t4 = *(const s16x8*)(bp + 128);    // h1(it-2) hi

        if (it >= 1 && it <= T_STEPS) {          // gates1(it-1)
            f32x4 d1a = __builtin_amdgcn_mfma_f32_16x16x32_bf16(e0[0], t1, bias1[0], 0, 0, 0);
            f32x4 d1b = __builtin_amdgcn_mfma_f32_16x16x32_bf16(e0[1], t1, bias1[1], 0, 0, 0);
            d1a = __builtin_amdgcn_mfma_f32_16x16x32_bf16(e1[0], t2, d1a, 0, 0, 0);
            d1b = __builtin_amdgcn_mfma_f32_16x16x32_bf16(e1[1], t2, d1b, 0, 0, 0);
            d1a = __builtin_amdgcn_mfma_f32_16x16x32_bf16(e2[0], t3, d1a, 0, 0, 0);
            d1b = __builtin_amdgcn_mfma_f32_16x16x32_bf16(e2[1], t3, d1b, 0, 0, 0);
            d1a = __builtin_amdgcn_mfma_f32_16x16x32_bf16(e3[0], t4, d1a, 0, 0, 0);
            d1b = __builtin_amdgcn_mfma_f32_16x16x32_bf16(e3[1], t4, d1b, 0, 0, 0);
            if (n16 < 4) {
                *(f32x4*)&gbuf1[gw0] = d1a;
                *(f32x4*)&gbuf1[gw1] = d1b;
            }
        }
        if (w < 4 && it < T_STEPS) {             // CELL0: h0(it), full-lane
            f32x4 g = *(const f32x4*)&gbuf0[gri * 4];
            float cc = sigf(g[1]) * cst0 + sigf(g[0]) * tanhf_(g[2]);
            cst0 = cc;
            bB[p ^ 1][cb][32 + cs] = f2bf(sigf(g[3]) * tanhf_(cc));
        }
        __syncthreads();             // gates1 + h0 visible
        xreg = xnew;
    }

    // ---- final FC on h1[T-1] (CELL1 at it=513, p=1 -> bB[1].h1) ----
    if (tid < 4) {
        float s = bfc[0];
#pragma unroll
        for (int k = 0; k < 64; ++k)
            s += bf2f(bB[1][tid][96 + k]) * Wfc[k];
        out[b0 + tid] = s;
    }
}

extern "C" void kernel_launch(void* const* d_in, const int* in_sizes, int n_in,
                              void* d_out, int out_size, void* d_ws, size_t ws_size,
                              hipStream_t stream) {
    const float* x    = (const float*)d_in[0];
    const float* Wih0 = (const float*)d_in[1];
    const float* Whh0 = (const float*)d_in[2];
    const float* bih0 = (const float*)d_in[3];
    const float* bhh0 = (const float*)d_in[4];
    const float* Wih1 = (const float*)d_in[5];
    const float* Whh1 = (const float*)d_in[6];
    const float* bih1 = (const float*)d_in[7];
    const float* bhh1 = (const float*)d_in[8];
    const float* Wfc  = (const float*)d_in[9];
    const float* bfc  = (const float*)d_in[10];
    float* out = (float*)d_out;

    const int B = out_size;            // 1024
    dim3 grid(B / 4), block(512);      // 256 blocks -> 1 per CU
    hipLaunchKernelGGL(lstm2_mfma, grid, block, 0, stream,
                       x, Wih0, Whh0, bih0, bhh0,
                       Wih1, Whh1, bih1, bhh1, Wfc, bfc, out);
}

// Round 9
// 472.388 us; speedup vs baseline: 1.2625x; 1.2625x over previous
//
#include <hip/hip_runtime.h>

#define T_STEPS 512

typedef __attribute__((ext_vector_type(8))) short s16x8;  // 8 bf16 (4 VGPRs)
typedef __attribute__((ext_vector_type(4))) float f32x4;  // MFMA C/D

__device__ __forceinline__ short f2bf(float v) {          // fp32 -> bf16 RNE
    unsigned u = __float_as_uint(v);
    return (short)((u + 0x7FFFu + ((u >> 16) & 1u)) >> 16);
}
__device__ __forceinline__ float bf2f(short b) {
    return __uint_as_float(((unsigned)(unsigned short)b) << 16);
}
// Fast transcendentals: v_exp_f32 (2^x) + v_rcp_f32. The 1.f/x forms compile
// to the ~10-op precise div sequence (v_div_scale/fmas/fixup) without
// fast-math -- 5 per cell was ~half the kernel's VALU (r6 counter audit).
// rcp error ~1ulp fp32, 4 orders below the bf16 rounding applied to h.
// NOTE: __exp2f collides with glibc math.h macros (r7 compile fail) -- use
// the amdgcn builtin directly.
#define LOG2E 1.4426950408889634f
__device__ __forceinline__ float rcpf(float x)  { return __builtin_amdgcn_rcpf(x); }
__device__ __forceinline__ float ex2f(float x)  { return __builtin_amdgcn_exp2f(x); }
__device__ __forceinline__ float sigf(float x)  { return rcpf(1.f + ex2f(-LOG2E * x)); }
__device__ __forceinline__ float tanhf_(float x){ return 1.f - 2.f * rcpf(ex2f(2.f * LOG2E * x) + 1.f); }

// Block: 4 batches, 512 threads = 8 waves; grid = 256 -> 1 block/CU.
// (r6 structure -- best known at 536us; r7's layer-interleave was neutral
// and is reverted.)
// 8 waves x 14 MFMAs (M=32/layer each; B frags M-invariant -> read ONCE,
// feed both tiles) -> 40 B-reads/CU-step. Registers ~84 VGPR, no spill
// under __launch_bounds__(512, 2) (256-reg unified cap).
// Phase 1: all 8 waves MFMA both layers' gates, publish to gbuf (LDS).
// Phase 2: ALL 8 waves dense-cell (0-3 = 256 L0 cells, 4-7 = 256 L1 cells);
// waves 0-1 also stage x (prefetched at loop top, ~1 iter of lead).
// B-col clamp: cols 0-3 real; lanes n16>=4 broadcast col 3 (garbage only in
// D-cols 4-15, never read). bB stride 176 shorts -> B-read bases land
// 2 requests/bank = wave64 floor (conflict-free, measured 0).
__global__ __launch_bounds__(512, 2)
void lstm2_mfma(const float* __restrict__ x,
                const float* __restrict__ Wih0, const float* __restrict__ Whh0,
                const float* __restrict__ bih0, const float* __restrict__ bhh0,
                const float* __restrict__ Wih1, const float* __restrict__ Whh1,
                const float* __restrict__ bih1, const float* __restrict__ bhh1,
                const float* __restrict__ Wfc,  const float* __restrict__ bfc,
                float* __restrict__ out)
{
    // merged B buffer, bf16, [parity][n(4)][k]: x 0..31 | h0 32..95 | h1 96..159
    __shared__ __align__(16) short bB[2][4][176];
    // gate buffers: [state*4 + batch] -> f32x4 (i,f,g,o), bias included (C-seed)
    __shared__ __align__(16) float gbuf0[256 * 4];   // L0
    __shared__ __align__(16) float gbuf1[256 * 4];   // L1

    const int tid  = threadIdx.x;
    const int w    = tid >> 6;       // wave 0..7
    const int lane = tid & 63;
    const int n16  = lane & 15;      // MFMA col (batch for n<4) / A-row m
    const int q4   = lane >> 4;      // quad: D-state-slot; A k-run
    const int b0   = blockIdx.x * 4;

    // ---- A fragments: two 16-row tiles per layer. Tile t row m -> gate m&3,
    //      state 8w + 4t + (m>>2). ----
    s16x8 a0[2], a1[2], a2[2];       // L0: K=96  {x, h0_lo, h0_hi}
    s16x8 e0[2], e1[2], e2[2], e3[2];// L1: K=128 {h0_lo, h0_hi, h1_lo, h1_hi}
    f32x4 bias0[2], bias1[2];
#pragma unroll
    for (int t = 0; t < 2; ++t) {
        const int rowW = (n16 & 3) * 64 + 8 * w + 4 * t + (n16 >> 2);
#pragma unroll
        for (int j = 0; j < 8; ++j) {
            a0[t][j] = f2bf(Wih0[rowW * 32 + q4 * 8 + j]);
            a1[t][j] = f2bf(Whh0[rowW * 64 + q4 * 8 + j]);
            a2[t][j] = f2bf(Whh0[rowW * 64 + 32 + q4 * 8 + j]);
            e0[t][j] = f2bf(Wih1[rowW * 64 + q4 * 8 + j]);
            e1[t][j] = f2bf(Wih1[rowW * 64 + 32 + q4 * 8 + j]);
            e2[t][j] = f2bf(Whh1[rowW * 64 + q4 * 8 + j]);
            e3[t][j] = f2bf(Whh1[rowW * 64 + 32 + q4 * 8 + j]);
        }
        const int jl = 8 * w + 4 * t + q4;   // state whose gates tile t's D holds
#pragma unroll
        for (int p_ = 0; p_ < 4; ++p_) {
            bias0[t][p_] = bih0[p_ * 64 + jl] + bhh0[p_ * 64 + jl];
            bias1[t][p_] = bih1[p_ * 64 + jl] + bhh1[p_ * 64 + jl];
        }
    }

    // ---- gate-buffer indices (writes: lanes n16<4) ----
    const int gw0 = ((8 * w + q4) * 4 + n16) * 4;        // tile0
    const int gw1 = ((8 * w + 4 + q4) * 4 + n16) * 4;    // tile1
    const int cw  = w & 3;                   // cell sub-wave id within layer group
    const int cs  = 16 * cw + (lane >> 2);   // cell state 0..63
    const int cb  = lane & 3;                // cell batch 0..3
    const int gri = 64 * cw + lane;          // == cs*4 + cb (consecutive b128)

    // ---- B-read column clamp ----
    const int nB  = (n16 < 4) ? n16 : 3;

    // ---- x stagers: waves 0-1 (also cell waves; load prefetched early).
    //      wave w stages batches 2w, 2w+1; full-lane: 2 batches x 32 k. ----
    const bool isx = (w < 2);
    const int  xb  = w * 2 + (lane >> 5);    // 0..3
    const int  xk  = lane & 31;
    const float* xp = x + ((size_t)(b0 + xb) * T_STEPS) * 32 + xk;

    // ---- init: zero B buffer; stage x_0 ----
    for (int i = tid; i < 2 * 4 * 176 / 2; i += 512) ((int*)bB)[i] = 0;
    __syncthreads();
    if (isx) bB[0][xb][xk] = f2bf(xp[0]);
    __syncthreads();

    float cst0 = 0.f, cst1 = 0.f;    // fp32 cell states (waves 0-3 / 4-7)

    for (int it = 0; it <= T_STEPS; ++it) {
        const int p = it & 1;

        float xpre = 0.f;
        const bool havex = isx && (it + 1 < T_STEPS);
        if (havex) xpre = xp[(size_t)(it + 1) * 32];   // ~1 iter ahead of use

        // ======== phase 1: gates via MFMA (all 8 waves), 5 B-frag reads ========
        const short* bp = &bB[p][nB][q4 * 8];
        s16x8 t0 = *(const s16x8*)(bp);          // x[it]
        s16x8 t1 = *(const s16x8*)(bp + 32);     // h0 lo
        s16x8 t2 = *(const s16x8*)(bp + 64);     // h0 hi
        s16x8 t3 = *(const s16x8*)(bp + 96);     // h1 lo
        s16x8 t4 = *(const s16x8*)(bp + 128);    // h1 hi

        f32x4 d0a = __builtin_amdgcn_mfma_f32_16x16x32_bf16(a0[0], t0, bias0[0], 0, 0, 0);
        f32x4 d0b = __builtin_amdgcn_mfma_f32_16x16x32_bf16(a0[1], t0, bias0[1], 0, 0, 0);
        d0a = __builtin_amdgcn_mfma_f32_16x16x32_bf16(a1[0], t1, d0a, 0, 0, 0);
        d0b = __builtin_amdgcn_mfma_f32_16x16x32_bf16(a1[1], t1, d0b, 0, 0, 0);
        d0a = __builtin_amdgcn_mfma_f32_16x16x32_bf16(a2[0], t2, d0a, 0, 0, 0);
        d0b = __builtin_amdgcn_mfma_f32_16x16x32_bf16(a2[1], t2, d0b, 0, 0, 0);

        f32x4 d1a = __builtin_amdgcn_mfma_f32_16x16x32_bf16(e0[0], t1, bias1[0], 0, 0, 0);
        f32x4 d1b = __builtin_amdgcn_mfma_f32_16x16x32_bf16(e0[1], t1, bias1[1], 0, 0, 0);
        d1a = __builtin_amdgcn_mfma_f32_16x16x32_bf16(e1[0], t2, d1a, 0, 0, 0);
        d1b = __builtin_amdgcn_mfma_f32_16x16x32_bf16(e1[1], t2, d1b, 0, 0, 0);
        d1a = __builtin_amdgcn_mfma_f32_16x16x32_bf16(e2[0], t3, d1a, 0, 0, 0);
        d1b = __builtin_amdgcn_mfma_f32_16x16x32_bf16(e2[1], t3, d1b, 0, 0, 0);
        d1a = __builtin_amdgcn_mfma_f32_16x16x32_bf16(e3[0], t4, d1a, 0, 0, 0);
        d1b = __builtin_amdgcn_mfma_f32_16x16x32_bf16(e3[1], t4, d1b, 0, 0, 0);

        if (n16 < 4) {               // publish gates: 4 b128 writes, 2-way (free)
            *(f32x4*)&gbuf0[gw0] = d0a;
            *(f32x4*)&gbuf0[gw1] = d0b;
            *(f32x4*)&gbuf1[gw0] = d1a;
            *(f32x4*)&gbuf1[gw1] = d1b;
        }
        __syncthreads();             // gates visible

        // ======== phase 2: ALL waves dense cells; waves 0-1 also stage x ========
        if (w < 4) {
            if (it < T_STEPS) {      // L0 at step `it`: 256 cells, full-lane
                f32x4 g = *(const f32x4*)&gbuf0[gri * 4];
                float cc = sigf(g[1]) * cst0 + sigf(g[0]) * tanhf_(g[2]);
                cst0 = cc;
                bB[p ^ 1][cb][32 + cs] = f2bf(sigf(g[3]) * tanhf_(cc));
            }
        } else {
            if (it >= 1) {           // L1 at step `it-1`: 256 cells, full-lane
                f32x4 g = *(const f32x4*)&gbuf1[gri * 4];
                float cc = sigf(g[1]) * cst1 + sigf(g[0]) * tanhf_(g[2]);
                cst1 = cc;
                bB[p ^ 1][cb][96 + cs] = f2bf(sigf(g[3]) * tanhf_(cc));
            }
        }
        if (havex) bB[p ^ 1][xb][xk] = f2bf(xpre);
        __syncthreads();             // h + x visible for next step
    }

    // ---- final FC on h1[T-1] (last L1 write: it=512, p=0 -> bB[1]) ----
    if (tid < 4) {
        float s = bfc[0];
#pragma unroll
        for (int k = 0; k < 64; ++k)
            s += bf2f(bB[1][tid][96 + k]) * Wfc[k];
        out[b0 + tid] = s;
    }
}

extern "C" void kernel_launch(void* const* d_in, const int* in_sizes, int n_in,
                              void* d_out, int out_size, void* d_ws, size_t ws_size,
                              hipStream_t stream) {
    const float* x    = (const float*)d_in[0];
    const float* Wih0 = (const float*)d_in[1];
    const float* Whh0 = (const float*)d_in[2];
    const float* bih0 = (const float*)d_in[3];
    const float* bhh0 = (const float*)d_in[4];
    const float* Wih1 = (const float*)d_in[5];
    const float* Whh1 = (const float*)d_in[6];
    const float* bih1 = (const float*)d_in[7];
    const float* bhh1 = (const float*)d_in[8];
    const float* Wfc  = (const float*)d_in[9];
    const float* bfc  = (const float*)d_in[10];
    float* out = (float*)d_out;

    const int B = out_size;            // 1024
    dim3 grid(B / 4), block(512);      // 256 blocks -> 1 per CU
    hipLaunchKernelGGL(lstm2_mfma, grid, block, 0, stream,
                       x, Wih0, Whh0, bih0, bhh0,
                       Wih1, Whh1, bih1, bhh1, Wfc, bfc, out);
}